// Round 16
// baseline (153.776 us; speedup 1.0000x reference)
//
#include <hip/hip_runtime.h>
#include <math.h>
#include <stdint.h>

// Problem constants (match reference)
constexpr int T_ = 128, B_ = 32, IN_ = 512, H_ = 8, D_ = 64, ETA_ = 4, R_ = 4;
constexpr int DE_ = ETA_ * D_;          // 256
constexpr float EPS_ = 1e-5f;
constexpr int M_   = T_ * B_;           // 4096
constexpr int BH_  = B_ * H_;           // 256
constexpr int NC2  = 16;                // fused-scan chunks (1 wave each)
constexpr int CH2  = T_ / NC2;          // 8 steps per chunk

// Permuted fused-projection output:
//   fp32 kqv_s (stride SW=1664): [0,512) keys | [512,1024) queries |
//       [1024,1536) gammas | [1536,1632) p | [1632,1664) pad
//   bf16 vb_bf (stride 1024):    [0,512) values | [512,1024) beta
// GEMM column space: col<1664 -> fp32 (3-pass split K=1536);
//                    col>=1664 -> bf16 (1-pass K=512)
constexpr int NW = 2688;                // total GEMM columns
constexpr int SW = 1664;                // fp32 width / split boundary
constexpr int SPLITCOL = 1664;

typedef __attribute__((ext_vector_type(8))) short bf16x8;
typedef __attribute__((ext_vector_type(4))) float f32x4;

__device__ __forceinline__ float bf2f(unsigned short u) {
    return __builtin_bit_cast(float, ((unsigned)u) << 16);
}
__device__ __forceinline__ unsigned short f2bf(float f) {
    unsigned u = __builtin_bit_cast(unsigned, f);
    u = (u + 0x7fffu + ((u >> 16) & 1u)) >> 16;   // RNE
    return (unsigned short)u;
}
__device__ __forceinline__ float fsigm(float x) {
    return __fdividef(1.f, 1.f + __expf(-x));
}

// ---------------------------------------------------------------------------
// inputs -> A2 = [A_hi | A_lo] (stride 1024 shorts)
// ---------------------------------------------------------------------------
__global__ __launch_bounds__(256) void cast_splitA(
    const float* __restrict__ src, unsigned short* __restrict__ dst, int n4)
{
    int i = blockIdx.x * 256 + threadIdx.x;
    if (i >= n4) return;
    const int r = i >> 7;
    const int c = (i & 127) << 2;
    float4 x = *(const float4*)(src + (size_t)r * 512 + c);
    ushort4 hi = make_ushort4(f2bf(x.x), f2bf(x.y), f2bf(x.z), f2bf(x.w));
    ushort4 lo = make_ushort4(f2bf(x.x - bf2f(hi.x)), f2bf(x.y - bf2f(hi.y)),
                              f2bf(x.z - bf2f(hi.z)), f2bf(x.w - bf2f(hi.w)));
    unsigned short* dr = dst + (size_t)r * 1024 + c;
    *(ushort4*)dr = hi;
    *(ushort4*)(dr + 512) = lo;
}

// ---------------------------------------------------------------------------
// Build W2 (2688 rows x [hi|lo], stride 1024) with the output-column
// permutation, plus bias_perm. Rows 1632..1663 are zero padding.
// (Third [hi] block removed vs R14 — pass 3 re-reads hi via koB remap.)
// ---------------------------------------------------------------------------
__global__ __launch_bounds__(256) void build_w2_bias(
    const float* __restrict__ Wkqv, const float* __restrict__ Wp,
    const float* __restrict__ bkqv, const float* __restrict__ bp,
    unsigned short* __restrict__ W2, float* __restrict__ bias_perm)
{
    int i = blockIdx.x * 256 + threadIdx.x;
    if (i >= NW * 128) return;
    const int rr = i >> 7;
    const int c = (i & 127) << 2;

    bool zero = false;
    const float* srow = nullptr;
    float bv = 0.f;
    if (rr < 512) {
        const int h = rr >> 6, dd = rr & 63, s = h * 320 + dd;
        srow = Wkqv + (size_t)s * 512; bv = bkqv[s];
    } else if (rr < 1024) {
        const int q = rr - 512, h = q >> 6, dd = q & 63, s = h * 320 + 64 + dd;
        srow = Wkqv + (size_t)s * 512; bv = bkqv[s];
    } else if (rr < 1536) {
        const int q = rr - 1024, h = q >> 6, dd = q & 63, s = h * 320 + 256 + dd;
        srow = Wkqv + (size_t)s * 512; bv = bkqv[s];
    } else if (rr < 1632) {
        const int q = rr - 1536;
        srow = Wp + (size_t)q * 512; bv = bp[q];
    } else if (rr < 1664) {
        zero = true;
    } else if (rr < 2176) {
        const int q = rr - 1664, h = q >> 6, dd = q & 63, s = h * 320 + 128 + dd;
        srow = Wkqv + (size_t)s * 512; bv = bkqv[s];
    } else {
        const int q = rr - 2176, h = q >> 6, dd = q & 63, s = h * 320 + 192 + dd;
        srow = Wkqv + (size_t)s * 512; bv = bkqv[s];
    }

    float4 x = zero ? make_float4(0.f, 0.f, 0.f, 0.f) : *(const float4*)(srow + c);
    ushort4 hi = make_ushort4(f2bf(x.x), f2bf(x.y), f2bf(x.z), f2bf(x.w));
    ushort4 lo = make_ushort4(f2bf(x.x - bf2f(hi.x)), f2bf(x.y - bf2f(hi.y)),
                              f2bf(x.z - bf2f(hi.z)), f2bf(x.w - bf2f(hi.w)));
    unsigned short* dr = W2 + (size_t)rr * 1024 + c;
    *(ushort4*)dr = hi;
    *(ushort4*)(dr + 512) = lo;
    if (c == 0) bias_perm[rr] = zero ? 0.f : bv;
}

// ---------------------------------------------------------------------------
// fp32 -> bf16 cast (W_o)
// ---------------------------------------------------------------------------
__global__ __launch_bounds__(256) void cast_f32_bf16(
    const float* __restrict__ src, unsigned short* __restrict__ dst, int n8)
{
    int i = blockIdx.x * 256 + threadIdx.x;
    if (i >= n8) return;
    const float4* s = (const float4*)src;
    float4 a = s[2 * i], b = s[2 * i + 1];
    *(ushort4*)(dst + 8 * i)     = make_ushort4(f2bf(a.x), f2bf(a.y), f2bf(a.z), f2bf(a.w));
    *(ushort4*)(dst + 8 * i + 4) = make_ushort4(f2bf(b.x), f2bf(b.y), f2bf(b.z), f2bf(b.w));
}

// ---------------------------------------------------------------------------
// bf16 MFMA GEMM (R14-proven structure): template <BM,BN>, BK=32, 4 waves,
// 3-buffer counted-vmcnt pipeline. Per-block K: bn < splitcol ? kBig : kSmall.
// koA remap (>=512 -> A_lo), koB remap (>=1024 -> W_hi again): passes are
// hi*hi, hi*lo, lo*hi. Epilogue: col < splitcol -> fp32 C1 (stride N1);
// else -> bf16 C2 (stride N2). Block-uniform branch (bn is 128-aligned).
// ---------------------------------------------------------------------------
__device__ __forceinline__ void gl_lds16(const unsigned short* g, unsigned short* l) {
    __builtin_amdgcn_global_load_lds((const __attribute__((address_space(1))) void*)g,
                                     (__attribute__((address_space(3))) void*)l, 16, 0, 0);
}

template <int BM, int BN>
__global__ __launch_bounds__(256) void gemm_bf16(
    const unsigned short* __restrict__ A,
    const unsigned short* __restrict__ W,
    const float* __restrict__ bias,
    float* __restrict__ C1, unsigned short* __restrict__ C2,
    int N1, int N2, int sA, int sW, int kBig, int kSmall, int splitcol)
{
    constexpr int WM = BM / 2, WN = BN / 2;
    constexpr int AM = WM / 16, AN = WN / 16;
    constexpr int NLA = BM / 64;
    constexpr int NLB = BN / 64;
    constexpr int NLD = NLA + NLB;

    int bx, by;
    {
        const int nwg = gridDim.x * gridDim.y;
        int lin = blockIdx.y * gridDim.x + blockIdx.x;
        lin = (lin & 7) * (nwg >> 3) + (lin >> 3);
        const int G = (gridDim.x % 7 == 0) ? 7 : gridDim.x;
        const int grpsz = gridDim.y * G;
        const int cg = lin / grpsz, rem = lin % grpsz;
        by = rem / G;
        bx = cg * G + rem % G;
    }
    const int bm = by * BM;
    const int bn = bx * BN;
    const int tid = threadIdx.x;
    const int lane = tid & 63;
    const int wid = tid >> 6;
    const int wr = wid >> 1;
    const int wc = wid & 1;

    __shared__ __align__(16) unsigned short As[3][BM * 32];
    __shared__ __align__(16) unsigned short Bs[3][BN * 32];

    const unsigned short* aRow = A + (size_t)(bm + (tid & (BM - 1))) * sA
                                   + (tid / BM) * 8;
    const unsigned short* bRow = W + (size_t)(bn + (tid & (BN - 1))) * sW
                                   + (tid / BN) * 8;

    const int fA = (((lane >> 4) * BM) + wr * WM + (lane & 15)) * 8;
    const int fB = (((lane >> 4) * BN) + wc * WN + (lane & 15)) * 8;

    f32x4 acc[AM][AN] = {};
    const int K = (bn < splitcol) ? kBig : kSmall;
    const int NKT = K >> 5;

    auto stage = [&](int buf, int k0) {
        const int koA = (k0 >= 512) ? k0 - 512 : k0;     // A [hi|lo] pairing
        const int koB = (k0 >= 1024) ? k0 - 1024 : k0;   // W [hi|lo], pass3 -> hi
#pragma unroll
        for (int i = 0; i < NLA; ++i)
            gl_lds16(aRow + koA + i * (256 / BM) * 8,
                     &As[buf][(i * 256 + wid * 64) * 8]);
#pragma unroll
        for (int i = 0; i < NLB; ++i)
            gl_lds16(bRow + koB + i * (256 / BN) * 8,
                     &Bs[buf][(i * 256 + wid * 64) * 8]);
    };

    stage(0, 0);
    if (NKT > 1) stage(1, 32);

    for (int kt = 0; kt < NKT; ++kt) {
        const int cur = kt % 3;
        if (kt + 2 < NKT) {
            stage((kt + 2) % 3, (kt + 2) << 5);
            if constexpr (NLD == 4)      asm volatile("s_waitcnt vmcnt(8)\ns_barrier" ::: "memory");
            else if constexpr (NLD == 3) asm volatile("s_waitcnt vmcnt(6)\ns_barrier" ::: "memory");
            else                         asm volatile("s_waitcnt vmcnt(4)\ns_barrier" ::: "memory");
        } else if (kt + 2 == NKT) {
            if constexpr (NLD == 4)      asm volatile("s_waitcnt vmcnt(4)\ns_barrier" ::: "memory");
            else if constexpr (NLD == 3) asm volatile("s_waitcnt vmcnt(3)\ns_barrier" ::: "memory");
            else                         asm volatile("s_waitcnt vmcnt(2)\ns_barrier" ::: "memory");
        } else {
            asm volatile("s_waitcnt vmcnt(0)\ns_barrier" ::: "memory");
        }
        __builtin_amdgcn_sched_barrier(0);

        bf16x8 af[AM], bfr[AN];
#pragma unroll
        for (int m = 0; m < AM; ++m) af[m] = *(const bf16x8*)&As[cur][fA + m * 128];
#pragma unroll
        for (int n = 0; n < AN; ++n) bfr[n] = *(const bf16x8*)&Bs[cur][fB + n * 128];
#pragma unroll
        for (int m = 0; m < AM; ++m)
#pragma unroll
            for (int n = 0; n < AN; ++n)
                acc[m][n] = __builtin_amdgcn_mfma_f32_16x16x32_bf16(af[m], bfr[n], acc[m][n], 0, 0, 0);

        asm volatile("s_waitcnt lgkmcnt(0)\ns_barrier" ::: "memory");
    }

    // epilogue: C/D layout col=lane&15, row=(lane>>4)*4+j  [m89]
    if (bn < splitcol) {
#pragma unroll
        for (int n = 0; n < AN; ++n) {
            const int col = bn + wc * WN + n * 16 + (lane & 15);
            const float bv = bias[col];
#pragma unroll
            for (int m = 0; m < AM; ++m) {
                const int row0 = bm + wr * WM + m * 16 + ((lane >> 4) << 2);
#pragma unroll
                for (int j = 0; j < 4; ++j)
                    C1[(size_t)(row0 + j) * N1 + col] = acc[m][n][j] + bv;
            }
        }
    } else {
#pragma unroll
        for (int n = 0; n < AN; ++n) {
            const int col = bn + wc * WN + n * 16 + (lane & 15);
            const float bv = bias[col];
            const int col2 = col - splitcol;
#pragma unroll
            for (int m = 0; m < AM; ++m) {
                const int row0 = bm + wr * WM + m * 16 + ((lane >> 4) << 2);
#pragma unroll
                for (int j = 0; j < 4; ++j)
                    C2[(size_t)(row0 + j) * N2 + col2] = f2bf(acc[m][n][j] + bv);
            }
        }
    }
}

// ---------------------------------------------------------------------------
// DPP wave64 sum: row_shr 1/2/4/8, bcast15, bcast31 -> lane 63 -> readlane.
// ---------------------------------------------------------------------------
template <int CTRL, int RM>
__device__ __forceinline__ float dpp_radd(float x) {
    int t = __builtin_amdgcn_update_dpp(0, __builtin_bit_cast(int, x), CTRL, RM, 0xf, true);
    return x + __builtin_bit_cast(float, t);
}
__device__ __forceinline__ float wave_allsum(float x) {
    x = dpp_radd<0x111, 0xf>(x);
    x = dpp_radd<0x112, 0xf>(x);
    x = dpp_radd<0x114, 0xf>(x);
    x = dpp_radd<0x118, 0xf>(x);
    x = dpp_radd<0x142, 0xa>(x);
    x = dpp_radd<0x143, 0xc>(x);
    return __builtin_bit_cast(float, __builtin_amdgcn_readlane(__builtin_bit_cast(int, x), 63));
}

// np.float32 omegas: cos(pi*tt), cos(pi/3*tt)
__device__ __forceinline__ void osc2(float tt, float& oc03, float& oc12) {
    oc03 = cosf(3.14159265358979323846f * tt);
    oc12 = cosf(1.04719755119659774615f * tt);
}

// ===========================================================================
// FUSED blocked scan (R14-proven structure; kqv fp32 stride 1664, values/
// beta from bf16 vb): one block per (b,h), 1024 threads = 16 waves = 16
// chunks of 8 steps. A: local scans; B: LDS combine; C: replay + attn.
// ===========================================================================
__global__ __launch_bounds__(1024) void scan_fused(
    const float* __restrict__ kqv,            // (T*B, 1664) f32
    const unsigned short* __restrict__ vb,    // (T*B, 1024) bf16: values|beta
    const float* __restrict__ term, const float* __restrict__ tick,
    const float* __restrict__ k_prev, const float* __restrict__ v_prev,
    const float* __restrict__ s_prev,
    unsigned short* __restrict__ attn,
    float* __restrict__ kf, float* __restrict__ vf, float* __restrict__ sf,
    float* __restrict__ tick_out)
{
    const int bh = blockIdx.x;
    const int b = bh >> 3, h = bh & 7;
    const int tid = threadIdx.x;
    const int w = tid >> 6;           // chunk id 0..15
    const int d = tid & 63;           // lane: owns de = 4d..4d+3

    __shared__ float LK[NC2][4][DE_];   // 64 KB
    __shared__ float LS[NC2][DE_];      // 16 KB
    __shared__ float LV[NC2][4][D_];    // 16 KB
    __shared__ float LDg[NC2][DE_];     // 16 KB
    __shared__ float LDb[NC2][D_];      // 4 KB

    const float tk = tick[b];

    // ------------------ Phase A: local chunk scan ------------------
    float K0[4] = {}, K1[4] = {}, K2[4] = {}, K3[4] = {}, S[4] = {};
    float V0 = 0.f, V1 = 0.f, V2 = 0.f, V3 = 0.f;
    float Dgv[4] = {1.f, 1.f, 1.f, 1.f};
    float Dbv = 1.f;

    if (w == 0) {   // chunk 0 starts from the true initial state
        float4 k4;
        k4 = *(const float4*)&k_prev[((size_t)(b * 4 + 0) * 8 + h) * DE_ + 4 * d];
        K0[0] = k4.x; K0[1] = k4.y; K0[2] = k4.z; K0[3] = k4.w;
        k4 = *(const float4*)&k_prev[((size_t)(b * 4 + 1) * 8 + h) * DE_ + 4 * d];
        K1[0] = k4.x; K1[1] = k4.y; K1[2] = k4.z; K1[3] = k4.w;
        k4 = *(const float4*)&k_prev[((size_t)(b * 4 + 2) * 8 + h) * DE_ + 4 * d];
        K2[0] = k4.x; K2[1] = k4.y; K2[2] = k4.z; K2[3] = k4.w;
        k4 = *(const float4*)&k_prev[((size_t)(b * 4 + 3) * 8 + h) * DE_ + 4 * d];
        K3[0] = k4.x; K3[1] = k4.y; K3[2] = k4.z; K3[3] = k4.w;
        k4 = *(const float4*)&s_prev[((size_t)b * 8 + h) * DE_ + 4 * d];
        S[0] = k4.x; S[1] = k4.y; S[2] = k4.z; S[3] = k4.w;
        V0 = v_prev[((size_t)(b * 4 + 0) * 8 + h) * D_ + d];
        V1 = v_prev[((size_t)(b * 4 + 1) * 8 + h) * D_ + d];
        V2 = v_prev[((size_t)(b * 4 + 2) * 8 + h) * D_ + d];
        V3 = v_prev[((size_t)(b * 4 + 3) * 8 + h) * D_ + d];
    }

    for (int t = w * CH2; t < w * CH2 + CH2; ++t) {
        const float* row = kqv + ((size_t)t * B_ + b) * SW;
        const unsigned short* vrow = vb + ((size_t)t * B_ + b) * 1024;
        const float c0 = row[h * 64 + d];                 // keys
        const float c4 = row[1024 + h * 64 + d];          // gammas
        const float c2 = bf2f(vrow[h * 64 + d]);          // values
        const float c3 = bf2f(vrow[512 + h * 64 + d]);    // beta
        const float* pr = row + 1536 + h * 12;
        const float4 p1 = *(const float4*)pr;
        const float4 p3 = *(const float4*)(pr + 8);
        const float nt = 1.f - term[(size_t)t * B_ + b];

        float oc03, oc12; osc2(tk + (float)(t + 1), oc03, oc12);
        const float sgam = fsigm(c4);
        const float rk = fmaxf(c0, 0.f);
        const float sbet = fsigm(c3);
        const float vbv = c2 * sbet;
        const float dbv = (1.f - sbet) * nt;
        const float p1a[4] = {p1.x, p1.y, p1.z, p1.w};
        const float p3a[4] = {p3.x, p3.y, p3.z, p3.w};
#pragma unroll
        for (int n = 0; n < 4; ++n) {
            const float g  = sgam * fsigm(p3a[n]);
            const float kg = rk * fmaxf(p1a[n], 0.f) * g;
            const float dg = (1.f - g) * nt;
            S[n]  = fmaf(dg, S[n],  kg);
            K0[n] = fmaf(dg, K0[n], kg * oc03);
            K1[n] = fmaf(dg, K1[n], kg * oc12);
            K2[n] = fmaf(dg, K2[n], kg * oc12);
            K3[n] = fmaf(dg, K3[n], kg * oc03);
            Dgv[n] *= dg;
        }
        V0 = fmaf(dbv, V0, vbv * oc03);
        V1 = fmaf(dbv, V1, vbv * oc12);
        V2 = fmaf(dbv, V2, vbv * oc12);
        V3 = fmaf(dbv, V3, vbv * oc03);
        Dbv *= dbv;
    }

    *(float4*)&LK[w][0][4 * d] = make_float4(K0[0], K0[1], K0[2], K0[3]);
    *(float4*)&LK[w][1][4 * d] = make_float4(K1[0], K1[1], K1[2], K1[3]);
    *(float4*)&LK[w][2][4 * d] = make_float4(K2[0], K2[1], K2[2], K2[3]);
    *(float4*)&LK[w][3][4 * d] = make_float4(K3[0], K3[1], K3[2], K3[3]);
    *(float4*)&LS[w][4 * d]    = make_float4(S[0], S[1], S[2], S[3]);
    LV[w][0][d] = V0; LV[w][1][d] = V1; LV[w][2][d] = V2; LV[w][3][d] = V3;
    *(float4*)&LDg[w][4 * d]   = make_float4(Dgv[0], Dgv[1], Dgv[2], Dgv[3]);
    LDb[w][d] = Dbv;
    __syncthreads();

    // ------------------ Phase B: serial combine over chunks ------------------
    if (tid < DE_) {
        const int de = tid;
        float c0 = LK[0][0][de], c1k = LK[0][1][de], c2k = LK[0][2][de],
              c3k = LK[0][3][de], cs = LS[0][de];
        for (int c = 1; c < NC2; ++c) {
            const float dg = LDg[c][de];
            float n0 = fmaf(dg, c0,  LK[c][0][de]); LK[c][0][de] = c0;  c0  = n0;
            float n1 = fmaf(dg, c1k, LK[c][1][de]); LK[c][1][de] = c1k; c1k = n1;
            float n2 = fmaf(dg, c2k, LK[c][2][de]); LK[c][2][de] = c2k; c2k = n2;
            float n3 = fmaf(dg, c3k, LK[c][3][de]); LK[c][3][de] = c3k; c3k = n3;
            float ns = fmaf(dg, cs,  LS[c][de]);    LS[c][de]    = cs;  cs  = ns;
        }
        kf[((size_t)(b * 4 + 0) * 8 + h) * DE_ + de] = c0;
        kf[((size_t)(b * 4 + 1) * 8 + h) * DE_ + de] = c1k;
        kf[((size_t)(b * 4 + 2) * 8 + h) * DE_ + de] = c2k;
        kf[((size_t)(b * 4 + 3) * 8 + h) * DE_ + de] = c3k;
        sf[((size_t)b * 8 + h) * DE_ + de] = cs;
    } else if (tid < DE_ + D_) {
        const int dd = tid - DE_;
        float v0 = LV[0][0][dd], v1 = LV[0][1][dd], v2 = LV[0][2][dd], v3 = LV[0][3][dd];
        for (int c = 1; c < NC2; ++c) {
            const float db = LDb[c][dd];
            float n0 = fmaf(db, v0, LV[c][0][dd]); LV[c][0][dd] = v0; v0 = n0;
            float n1 = fmaf(db, v1, LV[c][1][dd]); LV[c][1][dd] = v1; v1 = n1;
            float n2 = fmaf(db, v2, LV[c][2][dd]); LV[c][2][dd] = v2; v2 = n2;
            float n3 = fmaf(db, v3, LV[c][3][dd]); LV[c][3][dd] = v3; v3 = n3;
        }
        vf[((size_t)(b * 4 + 0) * 8 + h) * D_ + dd] = v0;
        vf[((size_t)(b * 4 + 1) * 8 + h) * D_ + dd] = v1;
        vf[((size_t)(b * 4 + 2) * 8 + h) * D_ + dd] = v2;
        vf[((size_t)(b * 4 + 3) * 8 + h) * D_ + dd] = v3;
    }
    if (h == 0 && tid == 0) tick_out[b] = tk + (float)T_;
    __syncthreads();

    // ------------------ Phase C: replay from incoming, emit attn ------------------
    if (w == 0) {   // chunk 0's incoming is the true initial state (reload)
        float4 k4;
        k4 = *(const float4*)&k_prev[((size_t)(b * 4 + 0) * 8 + h) * DE_ + 4 * d];
        K0[0] = k4.x; K0[1] = k4.y; K0[2] = k4.z; K0[3] = k4.w;
        k4 = *(const float4*)&k_prev[((size_t)(b * 4 + 1) * 8 + h) * DE_ + 4 * d];
        K1[0] = k4.x; K1[1] = k4.y; K1[2] = k4.z; K1[3] = k4.w;
        k4 = *(const float4*)&k_prev[((size_t)(b * 4 + 2) * 8 + h) * DE_ + 4 * d];
        K2[0] = k4.x; K2[1] = k4.y; K2[2] = k4.z; K2[3] = k4.w;
        k4 = *(const float4*)&k_prev[((size_t)(b * 4 + 3) * 8 + h) * DE_ + 4 * d];
        K3[0] = k4.x; K3[1] = k4.y; K3[2] = k4.z; K3[3] = k4.w;
        k4 = *(const float4*)&s_prev[((size_t)b * 8 + h) * DE_ + 4 * d];
        S[0] = k4.x; S[1] = k4.y; S[2] = k4.z; S[3] = k4.w;
        V0 = v_prev[((size_t)(b * 4 + 0) * 8 + h) * D_ + d];
        V1 = v_prev[((size_t)(b * 4 + 1) * 8 + h) * D_ + d];
        V2 = v_prev[((size_t)(b * 4 + 2) * 8 + h) * D_ + d];
        V3 = v_prev[((size_t)(b * 4 + 3) * 8 + h) * D_ + d];
    } else {
        float4 k4;
        k4 = *(const float4*)&LK[w][0][4 * d];
        K0[0] = k4.x; K0[1] = k4.y; K0[2] = k4.z; K0[3] = k4.w;
        k4 = *(const float4*)&LK[w][1][4 * d];
        K1[0] = k4.x; K1[1] = k4.y; K1[2] = k4.z; K1[3] = k4.w;
        k4 = *(const float4*)&LK[w][2][4 * d];
        K2[0] = k4.x; K2[1] = k4.y; K2[2] = k4.z; K2[3] = k4.w;
        k4 = *(const float4*)&LK[w][3][4 * d];
        K3[0] = k4.x; K3[1] = k4.y; K3[2] = k4.z; K3[3] = k4.w;
        k4 = *(const float4*)&LS[w][4 * d];
        S[0] = k4.x; S[1] = k4.y; S[2] = k4.z; S[3] = k4.w;
        V0 = LV[w][0][d]; V1 = LV[w][1][d]; V2 = LV[w][2][d]; V3 = LV[w][3][d];
    }

    for (int t = w * CH2; t < w * CH2 + CH2; ++t) {
        const float* row = kqv + ((size_t)t * B_ + b) * SW;
        const unsigned short* vrow = vb + ((size_t)t * B_ + b) * 1024;
        const float c0 = row[h * 64 + d];                 // keys
        const float c1 = row[512 + h * 64 + d];           // queries
        const float c4 = row[1024 + h * 64 + d];          // gammas
        const float c2 = bf2f(vrow[h * 64 + d]);          // values
        const float c3 = bf2f(vrow[512 + h * 64 + d]);    // beta
        const float* pr = row + 1536 + h * 12;
        const float4 p1 = *(const float4*)pr;
        const float4 p2 = *(const float4*)(pr + 4);
        const float4 p3 = *(const float4*)(pr + 8);
        const float nt = 1.f - term[(size_t)t * B_ + b];

        float oc03, oc12; osc2(tk + (float)(t + 1), oc03, oc12);
        const float sgam = fsigm(c4);
        const float rk = fmaxf(c0, 0.f);
        const float rq = fmaxf(c1, 0.f);
        const float sbet = fsigm(c3);
        const float vbv = c2 * sbet;
        const float dbv = (1.f - sbet) * nt;
        const float p1a[4] = {p1.x, p1.y, p1.z, p1.w};
        const float p2a[4] = {p2.x, p2.y, p2.z, p2.w};
        const float p3a[4] = {p3.x, p3.y, p3.z, p3.w};

        float s0 = 0.f, s1 = 0.f, s2 = 0.f, s3 = 0.f, s4 = 0.f;
#pragma unroll
        for (int n = 0; n < 4; ++n) {
            const float g  = sgam * fsigm(p3a[n]);
            const float kg = rk * fmaxf(p1a[n], 0.f) * g;
            const float qe = rq * fmaxf(p2a[n], 0.f);
            const float dg = (1.f - g) * nt;
            S[n]  = fmaf(dg, S[n],  kg);
            K0[n] = fmaf(dg, K0[n], kg * oc03);
            K1[n] = fmaf(dg, K1[n], kg * oc12);
            K2[n] = fmaf(dg, K2[n], kg * oc12);
            K3[n] = fmaf(dg, K3[n], kg * oc03);
            s0 = fmaf(K0[n], qe, s0);
            s1 = fmaf(K1[n], qe, s1);
            s2 = fmaf(K2[n], qe, s2);
            s3 = fmaf(K3[n], qe, s3);
            s4 = fmaf(S[n],  qe, s4);
        }
        V0 = fmaf(dbv, V0, vbv * oc03);
        V1 = fmaf(dbv, V1, vbv * oc12);
        V2 = fmaf(dbv, V2, vbv * oc12);
        V3 = fmaf(dbv, V3, vbv * oc03);

        const float kdq0 = wave_allsum(s0);
        const float kdq1 = wave_allsum(s1);
        const float kdq2 = wave_allsum(s2);
        const float kdq3 = wave_allsum(s3);
        const float nrm  = wave_allsum(s4);

        const float kv = V0 * kdq0 + V1 * kdq1 + V2 * kdq2 + V3 * kdq3;
        attn[((size_t)t * B_ + b) * (H_ * D_) + h * D_ + d] =
            f2bf(__fdividef(kv, 2.f * (float)R_ * nrm + EPS_));
    }
}

// ---------------------------------------------------------------------------
extern "C" void kernel_launch(void* const* d_in, const int* in_sizes, int n_in,
                              void* d_out, int out_size, void* d_ws, size_t ws_size,
                              hipStream_t stream)
{
    const float* inputs = (const float*)d_in[0];
    const float* term   = (const float*)d_in[1];
    const float* k_prev = (const float*)d_in[2];
    const float* v_prev = (const float*)d_in[3];
    const float* s_prev = (const float*)d_in[4];
    const float* tick   = (const float*)d_in[5];
    const float* W_kqv  = (const float*)d_in[6];
    const float* b_kqv  = (const float*)d_in[7];
    const float* W_p    = (const float*)d_in[8];
    const float* b_p    = (const float*)d_in[9];
    const float* W_o    = (const float*)d_in[10];
    const float* b_o    = (const float*)d_in[11];

    float* out = (float*)d_out;                       // (T,B,IN)
    float* kf  = out + (size_t)T_ * B_ * IN_;
    float* vf  = kf  + (size_t)B_ * R_ * H_ * DE_;
    float* sf  = vf  + (size_t)B_ * R_ * H_ * D_;
    float* tick_out = sf + (size_t)B_ * H_ * DE_;

    // workspace (~54 MB)
    float* kqv_s = (float*)d_ws;                                    // 4096x1664 f32  27.3MB
    unsigned short* vb_bf   = (unsigned short*)(kqv_s + (size_t)M_ * SW); // 4096x1024 bf16 8.4MB
    unsigned short* attn_bf = vb_bf + (size_t)M_ * 1024;            // 4096x512 bf16  4.2MB
    unsigned short* Wo_bf   = attn_bf + (size_t)M_ * IN_;           // 512x512 bf16   0.5MB
    unsigned short* A2      = Wo_bf + (size_t)IN_ * (H_ * D_);      // 4096x1024 [hi|lo] 8.4MB
    unsigned short* W2      = A2 + (size_t)M_ * 1024;               // 2688x1024 [hi|lo] 5.5MB
    float* bias_perm        = (float*)(W2 + (size_t)NW * 1024);     // 2688 f32

    {   // prep: A split, W2+bias build (permuted), W_o cast
        int n4 = M_ * 128;
        cast_splitA<<<(n4 + 255) / 256, 256, 0, stream>>>(inputs, A2, n4);
        n4 = NW * 128;
        build_w2_bias<<<(n4 + 255) / 256, 256, 0, stream>>>(W_kqv, W_p, b_kqv, b_p,
                                                            W2, bias_perm);
        int n8 = (IN_ * (H_ * D_)) / 8;
        cast_f32_bf16<<<(n8 + 255) / 256, 256, 0, stream>>>(W_o, Wo_bf, n8);
    }

    {   // fused projection: 128x128, BK=32, counted-vmcnt; fp32 cols < 1664,
        // bf16 cols >= 1664 (values/beta, numerator-only sensitivity)
        dim3 grid(NW / 128, M_ / 128);                  // 21 x 32 = 672 (%8==0, 21%7==0)
        gemm_bf16<128, 128><<<grid, 256, 0, stream>>>(A2, W2, bias_perm,
                                                      kqv_s, vb_bf,
                                                      SW, 1024, 1024, 1024,
                                                      1536, 512, SPLITCOL);
    }

    // fused blocked scan: one kernel, 16 waves/block = 16 chunks of 8 steps
    scan_fused<<<BH_, 1024, 0, stream>>>(kqv_s, vb_bf, term, tick,
                                         k_prev, v_prev, s_prev,
                                         attn_bf, kf, vf, sf, tick_out);

    {   // output projection: 64x64, BK=32, counted-vmcnt, grid 512 (all fp32)
        dim3 grid(IN_ / 64, M_ / 64);                   // 8 x 64 = 512 (%8==0)
        gemm_bf16<64, 64><<<grid, 256, 0, stream>>>(attn_bf, Wo_bf, b_o,
                                                    out, nullptr,
                                                    IN_, 0, 512, 512,
                                                    512, 512, IN_);
    }
}

// Round 17
// 138.285 us; speedup vs baseline: 1.1120x; 1.1120x over previous
//
#include <hip/hip_runtime.h>
#include <math.h>
#include <stdint.h>

// Problem constants (match reference)
constexpr int T_ = 128, B_ = 32, IN_ = 512, H_ = 8, D_ = 64, ETA_ = 4, R_ = 4;
constexpr int DE_ = ETA_ * D_;          // 256
constexpr float EPS_ = 1e-5f;
constexpr int M_   = T_ * B_;           // 4096
constexpr int BH_  = B_ * H_;           // 256
constexpr int NC2  = 16;                // fused-scan chunks (1 wave each)
constexpr int CH2  = T_ / NC2;          // 8 steps per chunk

// Permuted fused-projection layout (kqv_s, width NW):
//   [0,512)     keys    (3-pass split, precision-critical)
//   [512,1024)  queries (split)
//   [1024,1536) gammas  (split)
//   [1536,1632) p       (split)
//   [1632,1664) zero pad
//   [1664,2176) values  (1-pass bf16)
//   [2176,2688) beta    (1-pass)
constexpr int NW = 2688;
constexpr int SPLITCOL = 1664;          // cols < SPLITCOL use K=1536

typedef __attribute__((ext_vector_type(8))) short bf16x8;
typedef __attribute__((ext_vector_type(4))) float f32x4;

__device__ __forceinline__ float bf2f(unsigned short u) {
    return __builtin_bit_cast(float, ((unsigned)u) << 16);
}
__device__ __forceinline__ unsigned short f2bf(float f) {
    unsigned u = __builtin_bit_cast(unsigned, f);
    u = (u + 0x7fffu + ((u >> 16) & 1u)) >> 16;   // RNE
    return (unsigned short)u;
}
__device__ __forceinline__ float fsigm(float x) {
    return __fdividef(1.f, 1.f + __expf(-x));
}

// ---------------------------------------------------------------------------
// inputs -> A2 = [A_hi | A_lo] (stride 1024 shorts)
// ---------------------------------------------------------------------------
__global__ __launch_bounds__(256) void cast_splitA(
    const float* __restrict__ src, unsigned short* __restrict__ dst, int n4)
{
    int i = blockIdx.x * 256 + threadIdx.x;
    if (i >= n4) return;
    const int r = i >> 7;
    const int c = (i & 127) << 2;
    float4 x = *(const float4*)(src + (size_t)r * 512 + c);
    ushort4 hi = make_ushort4(f2bf(x.x), f2bf(x.y), f2bf(x.z), f2bf(x.w));
    ushort4 lo = make_ushort4(f2bf(x.x - bf2f(hi.x)), f2bf(x.y - bf2f(hi.y)),
                              f2bf(x.z - bf2f(hi.z)), f2bf(x.w - bf2f(hi.w)));
    unsigned short* dr = dst + (size_t)r * 1024 + c;
    *(ushort4*)dr = hi;
    *(ushort4*)(dr + 512) = lo;
}

// ---------------------------------------------------------------------------
// Build W2 (2688 rows x [hi|lo|hi], stride 1536) with the output-column
// permutation, plus bias_perm. Rows 1632..1663 are zero padding.
// ---------------------------------------------------------------------------
__global__ __launch_bounds__(256) void build_w2_bias(
    const float* __restrict__ Wkqv, const float* __restrict__ Wp,
    const float* __restrict__ bkqv, const float* __restrict__ bp,
    unsigned short* __restrict__ W2, float* __restrict__ bias_perm)
{
    int i = blockIdx.x * 256 + threadIdx.x;
    if (i >= NW * 128) return;
    const int rr = i >> 7;
    const int c = (i & 127) << 2;

    bool zero = false;
    const float* srow = nullptr;
    float bv = 0.f;
    if (rr < 512) {
        const int h = rr >> 6, dd = rr & 63, s = h * 320 + dd;
        srow = Wkqv + (size_t)s * 512; bv = bkqv[s];
    } else if (rr < 1024) {
        const int q = rr - 512, h = q >> 6, dd = q & 63, s = h * 320 + 64 + dd;
        srow = Wkqv + (size_t)s * 512; bv = bkqv[s];
    } else if (rr < 1536) {
        const int q = rr - 1024, h = q >> 6, dd = q & 63, s = h * 320 + 256 + dd;
        srow = Wkqv + (size_t)s * 512; bv = bkqv[s];
    } else if (rr < 1632) {
        const int q = rr - 1536;
        srow = Wp + (size_t)q * 512; bv = bp[q];
    } else if (rr < 1664) {
        zero = true;
    } else if (rr < 2176) {
        const int q = rr - 1664, h = q >> 6, dd = q & 63, s = h * 320 + 128 + dd;
        srow = Wkqv + (size_t)s * 512; bv = bkqv[s];
    } else {
        const int q = rr - 2176, h = q >> 6, dd = q & 63, s = h * 320 + 192 + dd;
        srow = Wkqv + (size_t)s * 512; bv = bkqv[s];
    }

    float4 x = zero ? make_float4(0.f, 0.f, 0.f, 0.f) : *(const float4*)(srow + c);
    ushort4 hi = make_ushort4(f2bf(x.x), f2bf(x.y), f2bf(x.z), f2bf(x.w));
    ushort4 lo = make_ushort4(f2bf(x.x - bf2f(hi.x)), f2bf(x.y - bf2f(hi.y)),
                              f2bf(x.z - bf2f(hi.z)), f2bf(x.w - bf2f(hi.w)));
    unsigned short* dr = W2 + (size_t)rr * 1536 + c;
    *(ushort4*)dr = hi;
    *(ushort4*)(dr + 512) = lo;
    *(ushort4*)(dr + 1024) = hi;
    if (c == 0) bias_perm[rr] = zero ? 0.f : bv;
}

// ---------------------------------------------------------------------------
// fp32 -> bf16 cast (W_o)
// ---------------------------------------------------------------------------
__global__ __launch_bounds__(256) void cast_f32_bf16(
    const float* __restrict__ src, unsigned short* __restrict__ dst, int n8)
{
    int i = blockIdx.x * 256 + threadIdx.x;
    if (i >= n8) return;
    const float4* s = (const float4*)src;
    float4 a = s[2 * i], b = s[2 * i + 1];
    *(ushort4*)(dst + 8 * i)     = make_ushort4(f2bf(a.x), f2bf(a.y), f2bf(a.z), f2bf(a.w));
    *(ushort4*)(dst + 8 * i + 4) = make_ushort4(f2bf(b.x), f2bf(b.y), f2bf(b.z), f2bf(b.w));
}

// ---------------------------------------------------------------------------
// bf16 MFMA GEMM (proven best): template <BM,BN>, BK=32, 4 waves, 3-buffer
// 2-deep pipeline with COUNTED vmcnt. Per-block K: bn < splitcol ? kBig :
// kSmall; A k-offset >= 512 remaps to A_lo ([hi|lo] pairing).
// ---------------------------------------------------------------------------
__device__ __forceinline__ void gl_lds16(const unsigned short* g, unsigned short* l) {
    __builtin_amdgcn_global_load_lds((const __attribute__((address_space(1))) void*)g,
                                     (__attribute__((address_space(3))) void*)l, 16, 0, 0);
}

template <int BM, int BN>
__global__ __launch_bounds__(256) void gemm_bf16(
    const unsigned short* __restrict__ A,
    const unsigned short* __restrict__ W,
    const float* __restrict__ bias,
    float* __restrict__ C,
    int N, int sA, int sW, int kBig, int kSmall, int splitcol)
{
    constexpr int WM = BM / 2, WN = BN / 2;
    constexpr int AM = WM / 16, AN = WN / 16;
    constexpr int NLA = BM / 64;
    constexpr int NLB = BN / 64;
    constexpr int NLD = NLA + NLB;

    int bx, by;
    {
        const int nwg = gridDim.x * gridDim.y;
        int lin = blockIdx.y * gridDim.x + blockIdx.x;
        lin = (lin & 7) * (nwg >> 3) + (lin >> 3);
        const int G = (gridDim.x % 7 == 0) ? 7 : gridDim.x;
        const int grpsz = gridDim.y * G;
        const int cg = lin / grpsz, rem = lin % grpsz;
        by = rem / G;
        bx = cg * G + rem % G;
    }
    const int bm = by * BM;
    const int bn = bx * BN;
    const int tid = threadIdx.x;
    const int lane = tid & 63;
    const int wid = tid >> 6;
    const int wr = wid >> 1;
    const int wc = wid & 1;

    __shared__ __align__(16) unsigned short As[3][BM * 32];
    __shared__ __align__(16) unsigned short Bs[3][BN * 32];

    const unsigned short* aRow = A + (size_t)(bm + (tid & (BM - 1))) * sA
                                   + (tid / BM) * 8;
    const unsigned short* bRow = W + (size_t)(bn + (tid & (BN - 1))) * sW
                                   + (tid / BN) * 8;

    const int fA = (((lane >> 4) * BM) + wr * WM + (lane & 15)) * 8;
    const int fB = (((lane >> 4) * BN) + wc * WN + (lane & 15)) * 8;

    f32x4 acc[AM][AN] = {};
    const int K = (bn < splitcol) ? kBig : kSmall;
    const int NKT = K >> 5;

    auto stage = [&](int buf, int k0) {
        const int koA = (k0 >= 512) ? k0 - 512 : k0;   // A [hi|lo] pairing
#pragma unroll
        for (int i = 0; i < NLA; ++i)
            gl_lds16(aRow + koA + i * (256 / BM) * 8,
                     &As[buf][(i * 256 + wid * 64) * 8]);
#pragma unroll
        for (int i = 0; i < NLB; ++i)
            gl_lds16(bRow + k0 + i * (256 / BN) * 8,
                     &Bs[buf][(i * 256 + wid * 64) * 8]);
    };

    stage(0, 0);
    if (NKT > 1) stage(1, 32);

    for (int kt = 0; kt < NKT; ++kt) {
        const int cur = kt % 3;
        if (kt + 2 < NKT) {
            stage((kt + 2) % 3, (kt + 2) << 5);
            if constexpr (NLD == 4)      asm volatile("s_waitcnt vmcnt(8)\ns_barrier" ::: "memory");
            else if constexpr (NLD == 3) asm volatile("s_waitcnt vmcnt(6)\ns_barrier" ::: "memory");
            else                         asm volatile("s_waitcnt vmcnt(4)\ns_barrier" ::: "memory");
        } else if (kt + 2 == NKT) {
            if constexpr (NLD == 4)      asm volatile("s_waitcnt vmcnt(4)\ns_barrier" ::: "memory");
            else if constexpr (NLD == 3) asm volatile("s_waitcnt vmcnt(3)\ns_barrier" ::: "memory");
            else                         asm volatile("s_waitcnt vmcnt(2)\ns_barrier" ::: "memory");
        } else {
            asm volatile("s_waitcnt vmcnt(0)\ns_barrier" ::: "memory");
        }
        __builtin_amdgcn_sched_barrier(0);

        bf16x8 af[AM], bfr[AN];
#pragma unroll
        for (int m = 0; m < AM; ++m) af[m] = *(const bf16x8*)&As[cur][fA + m * 128];
#pragma unroll
        for (int n = 0; n < AN; ++n) bfr[n] = *(const bf16x8*)&Bs[cur][fB + n * 128];
#pragma unroll
        for (int m = 0; m < AM; ++m)
#pragma unroll
            for (int n = 0; n < AN; ++n)
                acc[m][n] = __builtin_amdgcn_mfma_f32_16x16x32_bf16(af[m], bfr[n], acc[m][n], 0, 0, 0);

        asm volatile("s_waitcnt lgkmcnt(0)\ns_barrier" ::: "memory");
    }

    // epilogue: C/D layout col=lane&15, row=(lane>>4)*4+j  [m89]
#pragma unroll
    for (int n = 0; n < AN; ++n) {
        const int col = bn + wc * WN + n * 16 + (lane & 15);
        const float bv = bias[col];
#pragma unroll
        for (int m = 0; m < AM; ++m) {
            const int row0 = bm + wr * WM + m * 16 + ((lane >> 4) << 2);
#pragma unroll
            for (int j = 0; j < 4; ++j)
                C[(size_t)(row0 + j) * N + col] = acc[m][n][j] + bv;
        }
    }
}

// ---------------------------------------------------------------------------
// DPP wave64 sum: row_shr 1/2/4/8, bcast15, bcast31 -> lane 63 -> readlane.
// ---------------------------------------------------------------------------
template <int CTRL, int RM>
__device__ __forceinline__ float dpp_radd(float x) {
    int t = __builtin_amdgcn_update_dpp(0, __builtin_bit_cast(int, x), CTRL, RM, 0xf, true);
    return x + __builtin_bit_cast(float, t);
}
__device__ __forceinline__ float wave_allsum(float x) {
    x = dpp_radd<0x111, 0xf>(x);
    x = dpp_radd<0x112, 0xf>(x);
    x = dpp_radd<0x114, 0xf>(x);
    x = dpp_radd<0x118, 0xf>(x);
    x = dpp_radd<0x142, 0xa>(x);
    x = dpp_radd<0x143, 0xc>(x);
    return __builtin_bit_cast(float, __builtin_amdgcn_readlane(__builtin_bit_cast(int, x), 63));
}

// np.float32 omegas: cos(pi*tt), cos(pi/3*tt)
__device__ __forceinline__ void osc2(float tt, float& oc03, float& oc12) {
    oc03 = cosf(3.14159265358979323846f * tt);
    oc12 = cosf(1.04719755119659774615f * tt);
}

// ===========================================================================
// FUSED blocked scan: one block per (b,h), 1024 threads = 16 waves = 16
// chunks of 8 steps. Phase A: per-wave local scan (wave 0 from true init).
// Phase B: 15-step serial combine in LDS (+ final-state writes). Phase C:
// per-wave replay from incoming state, emitting attn.
// ===========================================================================
__global__ __launch_bounds__(1024) void scan_fused(
    const float* __restrict__ kqv, const float* __restrict__ term,
    const float* __restrict__ tick,
    const float* __restrict__ k_prev, const float* __restrict__ v_prev,
    const float* __restrict__ s_prev,
    unsigned short* __restrict__ attn,
    float* __restrict__ kf, float* __restrict__ vf, float* __restrict__ sf,
    float* __restrict__ tick_out)
{
    const int bh = blockIdx.x;
    const int b = bh >> 3, h = bh & 7;
    const int tid = threadIdx.x;
    const int w = tid >> 6;           // chunk id 0..15
    const int d = tid & 63;           // lane: owns de = 4d..4d+3

    __shared__ float LK[NC2][4][DE_];   // 64 KB
    __shared__ float LS[NC2][DE_];      // 16 KB
    __shared__ float LV[NC2][4][D_];    // 16 KB
    __shared__ float LDg[NC2][DE_];     // 16 KB
    __shared__ float LDb[NC2][D_];      // 4 KB

    const float tk = tick[b];

    // ------------------ Phase A: local chunk scan ------------------
    float K0[4] = {}, K1[4] = {}, K2[4] = {}, K3[4] = {}, S[4] = {};
    float V0 = 0.f, V1 = 0.f, V2 = 0.f, V3 = 0.f;
    float Dgv[4] = {1.f, 1.f, 1.f, 1.f};
    float Dbv = 1.f;

    if (w == 0) {   // chunk 0 starts from the true initial state
        float4 k4;
        k4 = *(const float4*)&k_prev[((size_t)(b * 4 + 0) * 8 + h) * DE_ + 4 * d];
        K0[0] = k4.x; K0[1] = k4.y; K0[2] = k4.z; K0[3] = k4.w;
        k4 = *(const float4*)&k_prev[((size_t)(b * 4 + 1) * 8 + h) * DE_ + 4 * d];
        K1[0] = k4.x; K1[1] = k4.y; K1[2] = k4.z; K1[3] = k4.w;
        k4 = *(const float4*)&k_prev[((size_t)(b * 4 + 2) * 8 + h) * DE_ + 4 * d];
        K2[0] = k4.x; K2[1] = k4.y; K2[2] = k4.z; K2[3] = k4.w;
        k4 = *(const float4*)&k_prev[((size_t)(b * 4 + 3) * 8 + h) * DE_ + 4 * d];
        K3[0] = k4.x; K3[1] = k4.y; K3[2] = k4.z; K3[3] = k4.w;
        k4 = *(const float4*)&s_prev[((size_t)b * 8 + h) * DE_ + 4 * d];
        S[0] = k4.x; S[1] = k4.y; S[2] = k4.z; S[3] = k4.w;
        V0 = v_prev[((size_t)(b * 4 + 0) * 8 + h) * D_ + d];
        V1 = v_prev[((size_t)(b * 4 + 1) * 8 + h) * D_ + d];
        V2 = v_prev[((size_t)(b * 4 + 2) * 8 + h) * D_ + d];
        V3 = v_prev[((size_t)(b * 4 + 3) * 8 + h) * D_ + d];
    }

    for (int t = w * CH2; t < w * CH2 + CH2; ++t) {
        const float* row = kqv + ((size_t)t * B_ + b) * NW;
        const float c0 = row[h * 64 + d];                 // keys
        const float c2 = row[1664 + h * 64 + d];          // values
        const float c3 = row[2176 + h * 64 + d];          // beta
        const float c4 = row[1024 + h * 64 + d];          // gammas
        const float* pr = row + 1536 + h * 12;
        const float4 p1 = *(const float4*)pr;
        const float4 p3 = *(const float4*)(pr + 8);
        const float nt = 1.f - term[(size_t)t * B_ + b];

        float oc03, oc12; osc2(tk + (float)(t + 1), oc03, oc12);
        const float sgam = fsigm(c4);
        const float rk = fmaxf(c0, 0.f);
        const float sbet = fsigm(c3);
        const float vb = c2 * sbet;
        const float dbv = (1.f - sbet) * nt;
        const float p1a[4] = {p1.x, p1.y, p1.z, p1.w};
        const float p3a[4] = {p3.x, p3.y, p3.z, p3.w};
#pragma unroll
        for (int n = 0; n < 4; ++n) {
            const float g  = sgam * fsigm(p3a[n]);
            const float kg = rk * fmaxf(p1a[n], 0.f) * g;
            const float dg = (1.f - g) * nt;
            S[n]  = fmaf(dg, S[n],  kg);
            K0[n] = fmaf(dg, K0[n], kg * oc03);
            K1[n] = fmaf(dg, K1[n], kg * oc12);
            K2[n] = fmaf(dg, K2[n], kg * oc12);
            K3[n] = fmaf(dg, K3[n], kg * oc03);
            Dgv[n] *= dg;
        }
        V0 = fmaf(dbv, V0, vb * oc03);
        V1 = fmaf(dbv, V1, vb * oc12);
        V2 = fmaf(dbv, V2, vb * oc12);
        V3 = fmaf(dbv, V3, vb * oc03);
        Dbv *= dbv;
    }

    *(float4*)&LK[w][0][4 * d] = make_float4(K0[0], K0[1], K0[2], K0[3]);
    *(float4*)&LK[w][1][4 * d] = make_float4(K1[0], K1[1], K1[2], K1[3]);
    *(float4*)&LK[w][2][4 * d] = make_float4(K2[0], K2[1], K2[2], K2[3]);
    *(float4*)&LK[w][3][4 * d] = make_float4(K3[0], K3[1], K3[2], K3[3]);
    *(float4*)&LS[w][4 * d]    = make_float4(S[0], S[1], S[2], S[3]);
    LV[w][0][d] = V0; LV[w][1][d] = V1; LV[w][2][d] = V2; LV[w][3][d] = V3;
    *(float4*)&LDg[w][4 * d]   = make_float4(Dgv[0], Dgv[1], Dgv[2], Dgv[3]);
    LDb[w][d] = Dbv;
    __syncthreads();

    // ------------------ Phase B: serial combine over chunks ------------------
    if (tid < DE_) {
        const int de = tid;
        float c0 = LK[0][0][de], c1k = LK[0][1][de], c2k = LK[0][2][de],
              c3k = LK[0][3][de], cs = LS[0][de];
        for (int c = 1; c < NC2; ++c) {
            const float dg = LDg[c][de];
            float n0 = fmaf(dg, c0,  LK[c][0][de]); LK[c][0][de] = c0;  c0  = n0;
            float n1 = fmaf(dg, c1k, LK[c][1][de]); LK[c][1][de] = c1k; c1k = n1;
            float n2 = fmaf(dg, c2k, LK[c][2][de]); LK[c][2][de] = c2k; c2k = n2;
            float n3 = fmaf(dg, c3k, LK[c][3][de]); LK[c][3][de] = c3k; c3k = n3;
            float ns = fmaf(dg, cs,  LS[c][de]);    LS[c][de]    = cs;  cs  = ns;
        }
        kf[((size_t)(b * 4 + 0) * 8 + h) * DE_ + de] = c0;
        kf[((size_t)(b * 4 + 1) * 8 + h) * DE_ + de] = c1k;
        kf[((size_t)(b * 4 + 2) * 8 + h) * DE_ + de] = c2k;
        kf[((size_t)(b * 4 + 3) * 8 + h) * DE_ + de] = c3k;
        sf[((size_t)b * 8 + h) * DE_ + de] = cs;
    } else if (tid < DE_ + D_) {
        const int dd = tid - DE_;
        float v0 = LV[0][0][dd], v1 = LV[0][1][dd], v2 = LV[0][2][dd], v3 = LV[0][3][dd];
        for (int c = 1; c < NC2; ++c) {
            const float db = LDb[c][dd];
            float n0 = fmaf(db, v0, LV[c][0][dd]); LV[c][0][dd] = v0; v0 = n0;
            float n1 = fmaf(db, v1, LV[c][1][dd]); LV[c][1][dd] = v1; v1 = n1;
            float n2 = fmaf(db, v2, LV[c][2][dd]); LV[c][2][dd] = v2; v2 = n2;
            float n3 = fmaf(db, v3, LV[c][3][dd]); LV[c][3][dd] = v3; v3 = n3;
        }
        vf[((size_t)(b * 4 + 0) * 8 + h) * D_ + dd] = v0;
        vf[((size_t)(b * 4 + 1) * 8 + h) * D_ + dd] = v1;
        vf[((size_t)(b * 4 + 2) * 8 + h) * D_ + dd] = v2;
        vf[((size_t)(b * 4 + 3) * 8 + h) * D_ + dd] = v3;
    }
    if (h == 0 && tid == 0) tick_out[b] = tk + (float)T_;
    __syncthreads();

    // ------------------ Phase C: replay from incoming, emit attn ------------------
    if (w == 0) {   // chunk 0's incoming is the true initial state (reload)
        float4 k4;
        k4 = *(const float4*)&k_prev[((size_t)(b * 4 + 0) * 8 + h) * DE_ + 4 * d];
        K0[0] = k4.x; K0[1] = k4.y; K0[2] = k4.z; K0[3] = k4.w;
        k4 = *(const float4*)&k_prev[((size_t)(b * 4 + 1) * 8 + h) * DE_ + 4 * d];
        K1[0] = k4.x; K1[1] = k4.y; K1[2] = k4.z; K1[3] = k4.w;
        k4 = *(const float4*)&k_prev[((size_t)(b * 4 + 2) * 8 + h) * DE_ + 4 * d];
        K2[0] = k4.x; K2[1] = k4.y; K2[2] = k4.z; K2[3] = k4.w;
        k4 = *(const float4*)&k_prev[((size_t)(b * 4 + 3) * 8 + h) * DE_ + 4 * d];
        K3[0] = k4.x; K3[1] = k4.y; K3[2] = k4.z; K3[3] = k4.w;
        k4 = *(const float4*)&s_prev[((size_t)b * 8 + h) * DE_ + 4 * d];
        S[0] = k4.x; S[1] = k4.y; S[2] = k4.z; S[3] = k4.w;
        V0 = v_prev[((size_t)(b * 4 + 0) * 8 + h) * D_ + d];
        V1 = v_prev[((size_t)(b * 4 + 1) * 8 + h) * D_ + d];
        V2 = v_prev[((size_t)(b * 4 + 2) * 8 + h) * D_ + d];
        V3 = v_prev[((size_t)(b * 4 + 3) * 8 + h) * D_ + d];
    } else {
        float4 k4;
        k4 = *(const float4*)&LK[w][0][4 * d];
        K0[0] = k4.x; K0[1] = k4.y; K0[2] = k4.z; K0[3] = k4.w;
        k4 = *(const float4*)&LK[w][1][4 * d];
        K1[0] = k4.x; K1[1] = k4.y; K1[2] = k4.z; K1[3] = k4.w;
        k4 = *(const float4*)&LK[w][2][4 * d];
        K2[0] = k4.x; K2[1] = k4.y; K2[2] = k4.z; K2[3] = k4.w;
        k4 = *(const float4*)&LK[w][3][4 * d];
        K3[0] = k4.x; K3[1] = k4.y; K3[2] = k4.z; K3[3] = k4.w;
        k4 = *(const float4*)&LS[w][4 * d];
        S[0] = k4.x; S[1] = k4.y; S[2] = k4.z; S[3] = k4.w;
        V0 = LV[w][0][d]; V1 = LV[w][1][d]; V2 = LV[w][2][d]; V3 = LV[w][3][d];
    }

    for (int t = w * CH2; t < w * CH2 + CH2; ++t) {
        const float* row = kqv + ((size_t)t * B_ + b) * NW;
        const float c0 = row[h * 64 + d];                 // keys
        const float c1 = row[512 + h * 64 + d];           // queries
        const float c2 = row[1664 + h * 64 + d];          // values
        const float c3 = row[2176 + h * 64 + d];          // beta
        const float c4 = row[1024 + h * 64 + d];          // gammas
        const float* pr = row + 1536 + h * 12;
        const float4 p1 = *(const float4*)pr;
        const float4 p2 = *(const float4*)(pr + 4);
        const float4 p3 = *(const float4*)(pr + 8);
        const float nt = 1.f - term[(size_t)t * B_ + b];

        float oc03, oc12; osc2(tk + (float)(t + 1), oc03, oc12);
        const float sgam = fsigm(c4);
        const float rk = fmaxf(c0, 0.f);
        const float rq = fmaxf(c1, 0.f);
        const float sbet = fsigm(c3);
        const float vb = c2 * sbet;
        const float dbv = (1.f - sbet) * nt;
        const float p1a[4] = {p1.x, p1.y, p1.z, p1.w};
        const float p2a[4] = {p2.x, p2.y, p2.z, p2.w};
        const float p3a[4] = {p3.x, p3.y, p3.z, p3.w};

        float s0 = 0.f, s1 = 0.f, s2 = 0.f, s3 = 0.f, s4 = 0.f;
#pragma unroll
        for (int n = 0; n < 4; ++n) {
            const float g  = sgam * fsigm(p3a[n]);
            const float kg = rk * fmaxf(p1a[n], 0.f) * g;
            const float qe = rq * fmaxf(p2a[n], 0.f);
            const float dg = (1.f - g) * nt;
            S[n]  = fmaf(dg, S[n],  kg);
            K0[n] = fmaf(dg, K0[n], kg * oc03);
            K1[n] = fmaf(dg, K1[n], kg * oc12);
            K2[n] = fmaf(dg, K2[n], kg * oc12);
            K3[n] = fmaf(dg, K3[n], kg * oc03);
            s0 = fmaf(K0[n], qe, s0);
            s1 = fmaf(K1[n], qe, s1);
            s2 = fmaf(K2[n], qe, s2);
            s3 = fmaf(K3[n], qe, s3);
            s4 = fmaf(S[n],  qe, s4);
        }
        V0 = fmaf(dbv, V0, vb * oc03);
        V1 = fmaf(dbv, V1, vb * oc12);
        V2 = fmaf(dbv, V2, vb * oc12);
        V3 = fmaf(dbv, V3, vb * oc03);

        const float kdq0 = wave_allsum(s0);
        const float kdq1 = wave_allsum(s1);
        const float kdq2 = wave_allsum(s2);
        const float kdq3 = wave_allsum(s3);
        const float nrm  = wave_allsum(s4);

        const float kv = V0 * kdq0 + V1 * kdq1 + V2 * kdq2 + V3 * kdq3;
        attn[((size_t)t * B_ + b) * (H_ * D_) + h * D_ + d] =
            f2bf(__fdividef(kv, 2.f * (float)R_ * nrm + EPS_));
    }
}

// ---------------------------------------------------------------------------
extern "C" void kernel_launch(void* const* d_in, const int* in_sizes, int n_in,
                              void* d_out, int out_size, void* d_ws, size_t ws_size,
                              hipStream_t stream)
{
    const float* inputs = (const float*)d_in[0];
    const float* term   = (const float*)d_in[1];
    const float* k_prev = (const float*)d_in[2];
    const float* v_prev = (const float*)d_in[3];
    const float* s_prev = (const float*)d_in[4];
    const float* tick   = (const float*)d_in[5];
    const float* W_kqv  = (const float*)d_in[6];
    const float* b_kqv  = (const float*)d_in[7];
    const float* W_p    = (const float*)d_in[8];
    const float* b_p    = (const float*)d_in[9];
    const float* W_o    = (const float*)d_in[10];
    const float* b_o    = (const float*)d_in[11];

    float* out = (float*)d_out;                       // (T,B,IN)
    float* kf  = out + (size_t)T_ * B_ * IN_;
    float* vf  = kf  + (size_t)B_ * R_ * H_ * DE_;
    float* sf  = vf  + (size_t)B_ * R_ * H_ * D_;
    float* tick_out = sf + (size_t)B_ * H_ * DE_;

    // workspace (~65.4 MB)
    float* kqv_s = (float*)d_ws;                                    // 4096 x 2688 f32  44.0MB
    unsigned short* attn_bf = (unsigned short*)(kqv_s + (size_t)M_ * NW); // 4096x512 bf16 4.2MB
    unsigned short* Wo_bf   = attn_bf + (size_t)M_ * IN_;           // 512x512 bf16     0.5MB
    unsigned short* A2      = Wo_bf + (size_t)IN_ * (H_ * D_);      // 4096x1024 [hi|lo] 8.4MB
    unsigned short* W2      = A2 + (size_t)M_ * 1024;               // 2688x1536 [hi|lo|hi] 8.3MB
    float* bias_perm        = (float*)(W2 + (size_t)NW * 1536);     // 2688 f32

    {   // prep: A split, W2+bias build (permuted), W_o cast
        int n4 = M_ * 128;
        cast_splitA<<<(n4 + 255) / 256, 256, 0, stream>>>(inputs, A2, n4);
        n4 = NW * 128;
        build_w2_bias<<<(n4 + 255) / 256, 256, 0, stream>>>(W_kqv, W_p, b_kqv, b_p,
                                                            W2, bias_perm);
        int n8 = (IN_ * (H_ * D_)) / 8;
        cast_f32_bf16<<<(n8 + 255) / 256, 256, 0, stream>>>(W_o, Wo_bf, n8);
    }

    {   // fused projection: 128x128, BK=32, counted-vmcnt pipeline
        dim3 grid(NW / 128, M_ / 128);                  // 21 x 32 = 672 (%8==0, 21%7==0)
        gemm_bf16<128, 128><<<grid, 256, 0, stream>>>(A2, W2, bias_perm, kqv_s,
                                                      NW, 1024, 1536, 1536, 512, SPLITCOL);
    }

    // fused blocked scan: one kernel, 16 waves/block = 16 chunks of 8 steps
    scan_fused<<<BH_, 1024, 0, stream>>>(kqv_s, term, tick, k_prev, v_prev, s_prev,
                                         attn_bf, kf, vf, sf, tick_out);

    {   // output projection: 64x64, BK=32, counted-vmcnt, grid 512 (2/CU)
        dim3 grid(IN_ / 64, M_ / 64);                   // 8 x 64 = 512 (%8==0)
        gemm_bf16<64, 64><<<grid, 256, 0, stream>>>(attn_bf, Wo_bf, b_o, out,
                                                    IN_, 512, 512, 512, 512, 0);
    }
}